// Round 1
// baseline (237.342 us; speedup 1.0000x reference)
//
#include <hip/hip_runtime.h>

// Gather + ragged segment XOR reduction.
//   entries:        [N, 5] int32 (harness truncates int64 -> int32; XOR commutes with truncation)
//   subset_blocks:  [T] int32
//   subset_offsets: [T] int32
//   subset_starts:  [H] int32 (CSR exclusive prefix)
//   subset_sizes:   [H] int32
//   block_size:     scalar int32 (1024)
//   out:            [H, 5] int32 XOR parities
//
// Strategy: one 64-lane wave per hint. Lanes strip-mine the segment
// (sizes < 128 so at most 2 passes), coalesced index loads, random 5-dword
// gather per element, butterfly __shfl_xor reduction, lane 0 writes.

__global__ __launch_bounds__(256) void hint_xor_wave(
    const int* __restrict__ entries,
    const int* __restrict__ blocks,
    const int* __restrict__ offsets,
    const int* __restrict__ starts,
    const int* __restrict__ sizes,
    const int* __restrict__ bs_ptr,
    int* __restrict__ out,
    int H, int N)
{
    const int gtid = blockIdx.x * blockDim.x + threadIdx.x;
    const int hint = gtid >> 6;     // wave id
    const int lane = gtid & 63;
    if (hint >= H) return;

    const int start = starts[hint];
    const int size  = sizes[hint];
    const int bs    = bs_ptr[0];    // 1024; uniform scalar load

    int a0 = 0, a1 = 0, a2 = 0, a3 = 0, a4 = 0;

    for (int j = lane; j < size; j += 64) {
        int idx = blocks[start + j] * bs + offsets[start + j];
        // reference clips to [0, N-1]; inputs guarantee in-range but keep it
        idx = min(max(idx, 0), N - 1);
        const int* row = entries + (size_t)idx * 5;
        a0 ^= row[0];
        a1 ^= row[1];
        a2 ^= row[2];
        a3 ^= row[3];
        a4 ^= row[4];
    }

    // full-wave butterfly XOR reduction (inactive lanes contributed 0)
    #pragma unroll
    for (int m = 1; m < 64; m <<= 1) {
        a0 ^= __shfl_xor(a0, m);
        a1 ^= __shfl_xor(a1, m);
        a2 ^= __shfl_xor(a2, m);
        a3 ^= __shfl_xor(a3, m);
        a4 ^= __shfl_xor(a4, m);
    }

    if (lane == 0) {
        int* o = out + (size_t)hint * 5;
        o[0] = a0; o[1] = a1; o[2] = a2; o[3] = a3; o[4] = a4;
    }
}

extern "C" void kernel_launch(void* const* d_in, const int* in_sizes, int n_in,
                              void* d_out, int out_size, void* d_ws, size_t ws_size,
                              hipStream_t stream) {
    const int* entries = (const int*)d_in[0];
    const int* blocks  = (const int*)d_in[1];
    const int* offsets = (const int*)d_in[2];
    const int* starts  = (const int*)d_in[3];
    const int* sizes   = (const int*)d_in[4];
    const int* bs      = (const int*)d_in[5];
    int* out = (int*)d_out;

    const int H = in_sizes[3];          // num hints
    const int N = in_sizes[0] / 5;      // entries rows

    const long total_threads = (long)H * 64;   // one wave per hint
    const int block = 256;
    const int grid = (int)((total_threads + block - 1) / block);

    hipLaunchKernelGGL(hint_xor_wave, dim3(grid), dim3(block), 0, stream,
                       entries, blocks, offsets, starts, sizes, bs, out, H, N);
}